// Round 16
// baseline (8085.662 us; speedup 1.0000x reference)
//
#include <hip/hip_runtime.h>
#include <math.h>

// Problem dims
#define SLEN 256
#define BSZ  128
#define DIN  128
#define HSZ  512
#define HH2  1024
#define GG3  1536
#define OSZ  25

typedef _Float16 h8 __attribute__((ext_vector_type(8)));
typedef float    f4 __attribute__((ext_vector_type(4)));

struct P_t {
  const float *x, *noise, *b_cin, *b1, *b2, *b3, *w4, *b4, *b_ih, *b_hh, *w_out, *b_out;
  _Float16 *WT1, *WT2, *WT3, *WTih, *WThh, *WTcin;   // row-major [N][K] (setup)
  _Float16 *FW1, *FW2, *FW3, *FWih, *FWhh;           // fragment-major (hot path)
  _Float16 *CIN, *Z1, *Z2;
  float *LOGI, *GX, *GH, *PART, *HF32, *CF32, *NF32; // GX/GH/CF32/HF32/NF32: x2 parity
  float *out;
};

__device__ __forceinline__ f4 mfma16(h8 a, h8 b, f4 c) {
  return __builtin_amdgcn_mfma_f32_16x16x32_f16(a, b, c, 0, 0, 0);
}
__device__ __forceinline__ float sigmf(float x) { return 1.f / (1.f + expf(-x)); }

// ---------------- setup kernels ----------------
__global__ __launch_bounds__(256) void transpose_cvt(const float* __restrict__ src,
    _Float16* __restrict__ dst, int K, int N) {
  __shared__ float tl[32][33];
  int nt = N >> 5;
  int bx = blockIdx.x % nt, by = blockIdx.x / nt;
  int n0 = bx << 5, k0 = by << 5;
  int tx = threadIdx.x & 31, ty = threadIdx.x >> 5;
#pragma unroll
  for (int i = 0; i < 4; ++i) {
    int r = ty + (i << 3);
    tl[r][tx] = src[(size_t)(k0 + r) * N + n0 + tx];
  }
  __syncthreads();
#pragma unroll
  for (int i = 0; i < 4; ++i) {
    int r = ty + (i << 3);
    dst[(size_t)(n0 + r) * K + k0 + tx] = (_Float16)tl[tx][r];
  }
}

// [N][K] row-major -> fragment-major (coalesced B loads in hot path)
__global__ __launch_bounds__(512) void fragpack(const _Float16* __restrict__ src,
    _Float16* __restrict__ dst, int K) {
  int ct = blockIdx.x;
  int chunks = (K / 32) * 64;
  for (int idx = threadIdx.x; idx < chunks; idx += 512) {
    int i = idx >> 6, lane = idx & 63;
    int mlw = lane & 15, qw = lane >> 4;
    *(h8*)(dst + ((size_t)ct * (K / 32) + i) * 512 + (size_t)lane * 8) =
        *(const h8*)(src + ((size_t)ct * 16 + mlw) * K + i * 32 + qw * 8);
  }
}

__global__ __launch_bounds__(256) void cin_kernel(P_t P) {
  int tid = blockIdx.x * blockDim.x + threadIdx.x;
  if (tid < SLEN * BSZ) {
    float u = P.noise[tid];
    P.LOGI[tid] = logf(u) - log1pf(-u);
  }
  int gw = tid >> 6, lane = tid & 63;
  int nw = (gridDim.x * blockDim.x) >> 6;
  int ml = lane & 15, q = lane >> 4;
  const int MT = (SLEN * BSZ) / 16;
  for (int tt = gw; tt < MT * 8; tt += nw) {
    int mt = tt & (MT - 1), nt = tt / MT;
    int m0 = mt * 16, n0 = nt * 64;
    int m = m0 + ml, b = m & 127, s = m >> 7;
    const float* ap = P.x + ((size_t)b * SLEN + s) * DIN + q * 8;
    const _Float16* bp = P.WTcin + (size_t)(n0 + ml) * DIN + q * 8;
    f4 a0 = {0,0,0,0}, a1 = a0, a2 = a0, a3 = a0;
#pragma unroll
    for (int k = 0; k < DIN; k += 32) {
      f4 lo = *(const f4*)(ap + k);
      f4 hi = *(const f4*)(ap + k + 4);
      h8 av;
      av[0] = (_Float16)lo[0]; av[1] = (_Float16)lo[1];
      av[2] = (_Float16)lo[2]; av[3] = (_Float16)lo[3];
      av[4] = (_Float16)hi[0]; av[5] = (_Float16)hi[1];
      av[6] = (_Float16)hi[2]; av[7] = (_Float16)hi[3];
      a0 = mfma16(av, *(const h8*)(bp + k),            a0);
      a1 = mfma16(av, *(const h8*)(bp + 16*DIN + k),   a1);
      a2 = mfma16(av, *(const h8*)(bp + 32*DIN + k),   a2);
      a3 = mfma16(av, *(const h8*)(bp + 48*DIN + k),   a3);
    }
#pragma unroll
    for (int r = 0; r < 4; ++r) {
      int row = m0 + q * 4 + r;
      int c0 = n0 + ml;
      P.CIN[(size_t)row * HSZ + c0     ] = (_Float16)tanhf(a0[r] + P.b_cin[c0]);
      P.CIN[(size_t)row * HSZ + c0 + 16] = (_Float16)tanhf(a1[r] + P.b_cin[c0 + 16]);
      P.CIN[(size_t)row * HSZ + c0 + 32] = (_Float16)tanhf(a2[r] + P.b_cin[c0 + 32]);
      P.CIN[(size_t)row * HSZ + c0 + 48] = (_Float16)tanhf(a3[r] + P.b_cin[c0 + 48]);
    }
  }
}

__global__ __launch_bounds__(256) void init_kernel(P_t P) {
  int idx = blockIdx.x * 256 + threadIdx.x;
  if (idx < BSZ * HSZ) {
    P.HF32[idx] = 0.f; P.HF32[idx + BSZ * HSZ] = 0.f;
    P.CF32[idx] = 0.f; P.CF32[idx + BSZ * HSZ] = 0.f;
  }
  if (idx < 2 * BSZ) P.NF32[idx] = 0.f;
}

// ---------------- step_a: fused state-update(t-1) + z1/gx/gh(t) ----------------
// Roles (full grid 512; tail grid 384 with +128 offset):
//   b<128:  z1 tiles, rt=b>>4, cg=b&15, ct=cg*4+wv  (8rt x 64ct)
//   b<320:  gx tiles, u=b-128, rt=u/24, cg=u%24      (8rt x 96ct)
//   b<512:  gh tiles, u=b-320
// State parity: reads state(t-2) at [t&1], writes state(t-1) at [(t+1)&1].
// Gates parity: reads gates(t-1) at [(t+1)&1], writes gates(t) at [t&1].
__global__ __launch_bounds__(256) void step_a(P_t P, int t, int tail) {
  __shared__ __align__(16) _Float16 sA[8192];   // 16 rows x 512 cols, A-fragment order
  __shared__ float s_al[16], s_om[16], s_nom[16], s_nnew[16];
  const int tid = threadIdx.x, lane = tid & 63, wv = tid >> 6;
  const int ml = lane & 15, q = lane >> 4;
  const int b = blockIdx.x + (tail ? 128 : 0);
  int role, rt, cg;
  if (b < 128)      { role = 0; rt = b >> 4; cg = b & 15; }
  else if (b < 320) { int u = b - 128; role = 1; rt = u / 24; cg = u - rt * 24; }
  else              { int u = b - 320; role = 2; rt = u / 24; cg = u - rt * 24; }
  const int m0 = rt * 16;
  const int pm1 = (t + 1) & 1;   // == (t-1)&1
  const int pm2 = t & 1;

  if (t > 0) {
    if (wv == 0) {
      const float* pp = P.PART + (size_t)(m0 + ml) * 64 + q * 16;
      f4 p0 = *(const f4*)pp, p1 = *(const f4*)(pp + 4),
         p2 = *(const f4*)(pp + 8), p3 = *(const f4*)(pp + 12);
      float s = p0[0]+p0[1]+p0[2]+p0[3] + p1[0]+p1[1]+p1[2]+p1[3]
              + p2[0]+p2[1]+p2[2]+p2[3] + p3[0]+p3[1]+p3[2]+p3[3];
      s += __shfl_xor(s, 16); s += __shfl_xor(s, 32);
      float lg = (s + P.b4[0] + P.LOGI[(size_t)(t - 1) * BSZ + m0 + ml]) * 10.0f;
      float al = sigmf(lg), om = 1.f - al;
      if (q == 0) {
        float n_old = P.NF32[pm2 * BSZ + m0 + ml];
        float nom = n_old * om, nnew = nom + 1.f;
        s_al[ml] = al; s_om[ml] = om; s_nom[ml] = nom; s_nnew[ml] = nnew;
        if (role == 0 && cg == 0) P.NF32[pm1 * BSZ + m0 + ml] = nnew;
      }
    }
    __syncthreads();
    if (role <= 1) {
      // build c(t-1) rows into sA (each lane: row ml, 4 chunks of 8 cols)
      float nom = s_nom[ml], rnn = 1.f / s_nnew[ml];
      const float*    cf = P.CF32 + ((size_t)pm2 * BSZ + m0 + ml) * HSZ;
      const _Float16* ci = P.CIN + ((size_t)(t - 1) * BSZ + m0 + ml) * HSZ;
      float* cw = (role == 0 && cg == 0)
                  ? (P.CF32 + ((size_t)pm1 * BSZ + m0 + ml) * HSZ) : nullptr;
#pragma unroll
      for (int ic = 0; ic < 4; ++ic) {
        int i = wv * 4 + ic, colb = i * 32 + q * 8;
        f4 c0 = *(const f4*)(cf + colb), c1 = *(const f4*)(cf + colb + 4);
        h8 cin8 = *(const h8*)(ci + colb);
        h8 hv; f4 o0, o1;
#pragma unroll
        for (int j = 0; j < 4; ++j) {
          o0[j] = (c0[j] * nom + (float)cin8[j])     * rnn;
          o1[j] = (c1[j] * nom + (float)cin8[4 + j]) * rnn;
          hv[j] = (_Float16)o0[j]; hv[4 + j] = (_Float16)o1[j];
        }
        *(h8*)(sA + i * 512 + lane * 8) = hv;
        if (cw) { *(f4*)(cw + colb) = o0; *(f4*)(cw + colb + 4) = o1; }
      }
    } else {
      // build h(t-1) rows from gates(t-1) + alpha(t-1)
      float al = s_al[ml], om = s_om[ml];
      const float* gx = P.GX + (size_t)pm1 * BSZ * GG3 + (size_t)(m0 + ml) * GG3;
      const float* gh = P.GH + (size_t)pm1 * BSZ * GG3 + (size_t)(m0 + ml) * GG3;
      const float* hf = P.HF32 + ((size_t)pm2 * BSZ + m0 + ml) * HSZ;
      float* hw = (cg == 0) ? (P.HF32 + ((size_t)pm1 * BSZ + m0 + ml) * HSZ) : nullptr;
#pragma unroll
      for (int ic = 0; ic < 4; ++ic) {
        int i = wv * 4 + ic, colb = i * 32 + q * 8;
        f4 xr0 = *(const f4*)(gx + colb),        xr1 = *(const f4*)(gx + colb + 4);
        f4 xz0 = *(const f4*)(gx + colb + 512),  xz1 = *(const f4*)(gx + colb + 516);
        f4 xn0 = *(const f4*)(gx + colb + 1024), xn1 = *(const f4*)(gx + colb + 1028);
        f4 hr0 = *(const f4*)(gh + colb),        hr1 = *(const f4*)(gh + colb + 4);
        f4 hz0 = *(const f4*)(gh + colb + 512),  hz1 = *(const f4*)(gh + colb + 516);
        f4 hn0 = *(const f4*)(gh + colb + 1024), hn1 = *(const f4*)(gh + colb + 1028);
        f4 h0 = *(const f4*)(hf + colb), h1 = *(const f4*)(hf + colb + 4);
        h8 hv; f4 o0, o1;
#pragma unroll
        for (int j = 0; j < 4; ++j) {
          float rg = sigmf(xr0[j] + hr0[j]);
          float zg = sigmf(xz0[j] + hz0[j]);
          float ng = tanhf(xn0[j] + rg * hn0[j]);
          o0[j] = h0[j] * om + al * ((1.f - zg) * ng + zg * h0[j]);
          rg = sigmf(xr1[j] + hr1[j]);
          zg = sigmf(xz1[j] + hz1[j]);
          ng = tanhf(xn1[j] + rg * hn1[j]);
          o1[j] = h1[j] * om + al * ((1.f - zg) * ng + zg * h1[j]);
          hv[j] = (_Float16)o0[j]; hv[4 + j] = (_Float16)o1[j];
        }
        *(h8*)(sA + i * 512 + lane * 8) = hv;
        if (hw) { *(f4*)(hw + colb) = o0; *(f4*)(hw + colb + 4) = o1; }
      }
    }
  } else {
    h8 z;
#pragma unroll
    for (int j = 0; j < 8; ++j) z[j] = (_Float16)0.f;
    for (int idx = tid; idx < 1024; idx += 256) *(h8*)(sA + idx * 8) = z;
  }
  __syncthreads();

  // ---- GEMM phase ----
  const int ct = cg * 4 + wv;
  f4 acc = {0.f, 0.f, 0.f, 0.f};
  if (role == 0) {
    const _Float16* bp = P.FW1 + (size_t)ct * 32 * 512 + lane * 8;
    const _Float16* sa = sA + lane * 8;
    const _Float16* ci = P.CIN + ((size_t)t * BSZ + m0 + ml) * HSZ + q * 8;
#pragma unroll
    for (int i = 0; i < 16; ++i)
      acc = mfma16(*(const h8*)(sa + i * 512), *(const h8*)(bp + (size_t)i * 512), acc);
#pragma unroll
    for (int i = 0; i < 16; ++i)
      acc = mfma16(*(const h8*)(ci + i * 32), *(const h8*)(bp + (size_t)(16 + i) * 512), acc);
    int col = ct * 16 + ml;
    float bia = P.b1[col];
#pragma unroll
    for (int j = 0; j < 4; ++j)
      P.Z1[(size_t)(m0 + q * 4 + j) * HH2 + col] = (_Float16)fmaxf(acc[j] + bia, 0.f);
  } else {
    const _Float16* bp = ((role == 1) ? P.FWih : P.FWhh) + (size_t)ct * 16 * 512 + lane * 8;
    const _Float16* sa = sA + lane * 8;
#pragma unroll
    for (int i = 0; i < 16; ++i)
      acc = mfma16(*(const h8*)(sa + i * 512), *(const h8*)(bp + (size_t)i * 512), acc);
    int col = ct * 16 + ml;
    float bia = (role == 1) ? P.b_ih[col] : P.b_hh[col];
    float* gd = ((role == 1) ? P.GX : P.GH) + (size_t)pm2 * BSZ * GG3;
#pragma unroll
    for (int j = 0; j < 4; ++j)
      gd[(size_t)(m0 + q * 4 + j) * GG3 + col] = acc[j] + bia;
  }
}

// step_b: z2 = relu(z1@W2+b2)
__global__ __launch_bounds__(256) void step_b(P_t P) {
  const int tid = threadIdx.x;
  const int lane = tid & 63, wv = tid >> 6;
  const int ml = lane & 15, q = lane >> 4;
  const int g = blockIdx.x * 4 + wv;
  int rt = g & 7, ct = g >> 3;
  int m0 = rt * 16, col = ct * 16 + ml;
  const _Float16* a0 = P.Z1 + (size_t)(m0 + ml) * HH2 + q * 8;
  const _Float16* bp = P.FW2 + (size_t)ct * 32 * 512 + (size_t)lane * 8;
  f4 acc = {0.f, 0.f, 0.f, 0.f};
#pragma unroll
  for (int i = 0; i < 32; ++i)
    acc = mfma16(*(const h8*)(a0 + i * 32), *(const h8*)(bp + (size_t)i * 512), acc);
  float bia = P.b2[col];
#pragma unroll
  for (int j = 0; j < 4; ++j)
    P.Z2[(size_t)(m0 + q * 4 + j) * HH2 + col] = (_Float16)fmaxf(acc[j] + bia, 0.f);
}

// step_c: PART[row][ct] = col-tile partial of relu(z2@W3+b3)·w4
__global__ __launch_bounds__(256) void step_c(P_t P) {
  const int tid = threadIdx.x;
  const int lane = tid & 63, wv = tid >> 6;
  const int ml = lane & 15, q = lane >> 4;
  const int g = blockIdx.x * 4 + wv;
  int rt = g & 7, ct = g >> 3;
  int m0 = rt * 16, col = ct * 16 + ml;
  const _Float16* a0 = P.Z2 + (size_t)(m0 + ml) * HH2 + q * 8;
  const _Float16* bp = P.FW3 + (size_t)ct * 32 * 512 + (size_t)lane * 8;
  f4 acc = {0.f, 0.f, 0.f, 0.f};
#pragma unroll
  for (int i = 0; i < 32; ++i)
    acc = mfma16(*(const h8*)(a0 + i * 32), *(const h8*)(bp + (size_t)i * 512), acc);
  float bia = P.b3[col], w4v = P.w4[col];
#pragma unroll
  for (int j = 0; j < 4; ++j) {
    float v = fmaxf(acc[j] + bia, 0.f) * w4v;
    v += __shfl_xor(v, 1); v += __shfl_xor(v, 2);
    v += __shfl_xor(v, 4); v += __shfl_xor(v, 8);
    if (ml == 0) P.PART[(size_t)(m0 + q * 4 + j) * 64 + ct] = v;
  }
}

// final: hfin = GRUcell(c255,h255) via gates(256) [GX/GH parity 0], h255 [HF32 parity 1]
__global__ __launch_bounds__(512) void final_kernel(P_t P) {
  __shared__ float hf[512];
  const int r = blockIdx.x, tid = threadIdx.x;
  const int lane = tid & 63, wv = tid >> 6;
  {
    int col = tid;
    size_t go = (size_t)r * GG3 + col;
    float xr = P.GX[go], xz = P.GX[go + 512], xn = P.GX[go + 1024];
    float hr = P.GH[go], hz = P.GH[go + 512], hn = P.GH[go + 1024];
    float rg = sigmf(xr + hr);
    float zg = sigmf(xz + hz);
    float ng = tanhf(xn + rg * hn);
    float h_old = P.HF32[(size_t)BSZ * HSZ + (size_t)r * HSZ + col];
    hf[col] = (1.f - zg) * ng + zg * h_old;
  }
  __syncthreads();
  for (int c = wv; c < OSZ; c += 8) {
    float v = 0.f;
#pragma unroll
    for (int j = 0; j < 8; ++j)
      v += hf[lane + 64 * j] * P.w_out[(size_t)(lane + 64 * j) * OSZ + c];
#pragma unroll
    for (int off = 32; off > 0; off >>= 1) v += __shfl_xor(v, off);
    if (lane == 0) P.out[r * OSZ + c] = v + P.b_out[c];
  }
}

// ---------------- host ----------------
extern "C" void kernel_launch(void* const* d_in, const int* in_sizes, int n_in,
                              void* d_out, int out_size, void* d_ws, size_t ws_size,
                              hipStream_t stream) {
  const float* x     = (const float*)d_in[0];
  const float* noise = (const float*)d_in[1];
  const float* w_cin = (const float*)d_in[2];
  const float* b_cin = (const float*)d_in[3];
  const float* w1    = (const float*)d_in[4];
  const float* b1    = (const float*)d_in[5];
  const float* w2    = (const float*)d_in[6];
  const float* b2    = (const float*)d_in[7];
  const float* w3    = (const float*)d_in[8];
  const float* b3    = (const float*)d_in[9];
  const float* w4    = (const float*)d_in[10];
  const float* b4    = (const float*)d_in[11];
  const float* w_ih  = (const float*)d_in[12];
  const float* b_ih  = (const float*)d_in[13];
  const float* w_hh  = (const float*)d_in[14];
  const float* b_hh  = (const float*)d_in[15];
  const float* w_out = (const float*)d_in[16];
  const float* b_out = (const float*)d_in[17];

  char* ws = (char*)d_ws;
  size_t off = 0;
  auto alloc = [&](size_t bytes) -> void* {
    void* p = ws + off;
    off = (off + bytes + 255) & ~(size_t)255;
    return p;
  };

  P_t P;
  P.x = x; P.noise = noise; P.b_cin = b_cin; P.b1 = b1; P.b2 = b2; P.b3 = b3;
  P.w4 = w4; P.b4 = b4; P.b_ih = b_ih; P.b_hh = b_hh; P.w_out = w_out; P.b_out = b_out;
  P.WT1   = (_Float16*)alloc((size_t)HH2 * HH2 * 2);
  P.WT2   = (_Float16*)alloc((size_t)HH2 * HH2 * 2);
  P.WT3   = (_Float16*)alloc((size_t)HH2 * HH2 * 2);
  P.WTih  = (_Float16*)alloc((size_t)GG3 * HSZ * 2);
  P.WThh  = (_Float16*)alloc((size_t)GG3 * HSZ * 2);
  P.WTcin = (_Float16*)alloc((size_t)HSZ * DIN * 2);
  P.FW1   = (_Float16*)alloc((size_t)HH2 * HH2 * 2);
  P.FW2   = (_Float16*)alloc((size_t)HH2 * HH2 * 2);
  P.FW3   = (_Float16*)alloc((size_t)HH2 * HH2 * 2);
  P.FWih  = (_Float16*)alloc((size_t)GG3 * HSZ * 2);
  P.FWhh  = (_Float16*)alloc((size_t)GG3 * HSZ * 2);
  P.CIN   = (_Float16*)alloc((size_t)SLEN * BSZ * HSZ * 2);
  P.Z1    = (_Float16*)alloc((size_t)BSZ * HH2 * 2);
  P.Z2    = (_Float16*)alloc((size_t)BSZ * HH2 * 2);
  P.LOGI  = (float*)alloc((size_t)SLEN * BSZ * 4);
  P.GX    = (float*)alloc((size_t)2 * BSZ * GG3 * 4);
  P.GH    = (float*)alloc((size_t)2 * BSZ * GG3 * 4);
  P.PART  = (float*)alloc((size_t)BSZ * 64 * 4);
  P.HF32  = (float*)alloc((size_t)2 * BSZ * HSZ * 4);
  P.CF32  = (float*)alloc((size_t)2 * BSZ * HSZ * 4);
  P.NF32  = (float*)alloc((size_t)2 * BSZ * 4);
  P.out   = (float*)d_out;

  transpose_cvt<<<(HH2/32)*(HH2/32), 256, 0, stream>>>(w1, P.WT1, HH2, HH2);
  transpose_cvt<<<(HH2/32)*(HH2/32), 256, 0, stream>>>(w2, P.WT2, HH2, HH2);
  transpose_cvt<<<(HH2/32)*(HH2/32), 256, 0, stream>>>(w3, P.WT3, HH2, HH2);
  transpose_cvt<<<(GG3/32)*(HSZ/32), 256, 0, stream>>>(w_ih, P.WTih, HSZ, GG3);
  transpose_cvt<<<(GG3/32)*(HSZ/32), 256, 0, stream>>>(w_hh, P.WThh, HSZ, GG3);
  transpose_cvt<<<(HSZ/32)*(DIN/32), 256, 0, stream>>>(w_cin, P.WTcin, DIN, HSZ);
  fragpack<<<HH2/16, 512, 0, stream>>>(P.WT1, P.FW1, HH2);
  fragpack<<<HH2/16, 512, 0, stream>>>(P.WT2, P.FW2, HH2);
  fragpack<<<HH2/16, 512, 0, stream>>>(P.WT3, P.FW3, HH2);
  fragpack<<<GG3/16, 512, 0, stream>>>(P.WTih, P.FWih, HSZ);
  fragpack<<<GG3/16, 512, 0, stream>>>(P.WThh, P.FWhh, HSZ);

  cin_kernel<<<1024, 256, 0, stream>>>(P);
  init_kernel<<<256, 256, 0, stream>>>(P);

  for (int t = 0; t < SLEN; ++t) {
    step_a<<<512, 256, 0, stream>>>(P, t, 0);   // state(t-1) + z1/gx/gh(t)
    step_b<<<128, 256, 0, stream>>>(P);         // z2
    step_c<<<128, 256, 0, stream>>>(P);         // z3·w4 -> PART
  }
  step_a<<<384, 256, 0, stream>>>(P, SLEN, 1);  // state(255) + gates(256)
  final_kernel<<<BSZ, 512, 0, stream>>>(P);
}